// Round 1
// baseline (1667.757 us; speedup 1.0000x reference)
//
#include <hip/hip_runtime.h>
#include <hip/hip_bf16.h>

#define NN 8192
#define HH 4096
#define GG 8
#define NNZ_CAP (1u << 20)

// ---------------------------------------------------------------------------
// Pass 1: count nonzeros.  rowcnt = nnz of x-pattern per row (for x@W1 CSR).
// colcnt = nnz of A-pattern per column (A = x-pattern with forced diagonal);
// colcnt == in-degree == deg for the GCN normalization.
// ---------------------------------------------------------------------------
__global__ __launch_bounds__(256) void k_count(const float* __restrict__ x,
                                               unsigned* __restrict__ colcnt,
                                               unsigned* __restrict__ rowcnt) {
    const int r = blockIdx.x;
    const float4* xr = reinterpret_cast<const float4*>(x + (size_t)r * NN);
    __shared__ unsigned rc;
    if (threadIdx.x == 0) rc = 0u;
    __syncthreads();
    unsigned local = 0;
    #pragma unroll
    for (int i = 0; i < NN / (4 * 256); ++i) {
        const int c4 = i * 256 + threadIdx.x;
        float4 v = xr[c4];
        const float* vp = reinterpret_cast<const float*>(&v);
        #pragma unroll
        for (int k = 0; k < 4; ++k) {
            const int c = c4 * 4 + k;
            const bool nzx = (vp[k] != 0.0f);
            if (nzx) local++;
            if (nzx || (c == r)) atomicAdd(&colcnt[c], 1u);
        }
    }
    if (local) atomicAdd(&rc, local);
    __syncthreads();
    if (threadIdx.x == 0) rowcnt[r] = rc;
}

// ---------------------------------------------------------------------------
// Exclusive prefix sums (rowcnt->rowptr, colcnt->colptr) + dinv = rsqrt(deg).
// Single block, 1024 threads, 8 elems/thread.
// ---------------------------------------------------------------------------
__device__ void scan_one(const unsigned* __restrict__ cnt, unsigned* __restrict__ ptr,
                         unsigned* part) {
    const int t = threadIdx.x;
    unsigned v[8];
    unsigned sum = 0;
    #pragma unroll
    for (int k = 0; k < 8; ++k) { v[k] = cnt[t * 8 + k]; sum += v[k]; }
    part[t] = sum;
    __syncthreads();
    for (int off = 1; off < 1024; off <<= 1) {
        unsigned val = (t >= off) ? part[t - off] : 0u;
        __syncthreads();
        part[t] += val;
        __syncthreads();
    }
    unsigned base = (t == 0) ? 0u : part[t - 1];
    #pragma unroll
    for (int k = 0; k < 8; ++k) { ptr[t * 8 + k] = base; base += v[k]; }
    if (t == 1023) ptr[NN] = base;
    __syncthreads();
}

__global__ __launch_bounds__(1024) void k_scan(const unsigned* __restrict__ rowcnt,
                                               const unsigned* __restrict__ colcnt,
                                               unsigned* __restrict__ rowptr,
                                               unsigned* __restrict__ colptr,
                                               float* __restrict__ dinv) {
    __shared__ unsigned part[1024];
    scan_one(rowcnt, rowptr, part);
    __syncthreads();
    scan_one(colcnt, colptr, part);
    for (int i = threadIdx.x; i < NN; i += 1024)
        dinv[i] = rsqrtf((float)colcnt[i]);
}

__global__ __launch_bounds__(256) void k_batchcnt(const int* __restrict__ batch,
                                                  unsigned* __restrict__ cnt) {
    const int i = blockIdx.x * 256 + threadIdx.x;
    if (i < NN) atomicAdd(&cnt[batch[i]], 1u);
}

// ---------------------------------------------------------------------------
// Pass 2: fill CSR (x-pattern col indices) and CSC (A-pattern row indices),
// and compute s[g][r] = dinv[r] * sum_{c in row_A(r), batch[c]==g} dinv[c]
// (the segment-summed B.T, i.e. the pooled adjacency).
// ---------------------------------------------------------------------------
__global__ __launch_bounds__(256) void k_fill(const float* __restrict__ x,
                                              const int* __restrict__ batch,
                                              const float* __restrict__ dinv,
                                              const unsigned* __restrict__ rowptr,
                                              const unsigned* __restrict__ colptr,
                                              unsigned* __restrict__ colfill,
                                              unsigned* __restrict__ csr,
                                              unsigned* __restrict__ csc,
                                              float* __restrict__ s) {
    const int r = blockIdx.x;
    __shared__ unsigned rpos;
    __shared__ float bins[GG];
    if (threadIdx.x == 0) rpos = 0u;
    if (threadIdx.x < GG) bins[threadIdx.x] = 0.0f;
    __syncthreads();
    const unsigned rbase = rowptr[r];
    const float4* xr = reinterpret_cast<const float4*>(x + (size_t)r * NN);
    #pragma unroll
    for (int i = 0; i < NN / (4 * 256); ++i) {
        const int c4 = i * 256 + threadIdx.x;
        float4 v = xr[c4];
        const float* vp = reinterpret_cast<const float*>(&v);
        #pragma unroll
        for (int k = 0; k < 4; ++k) {
            const int c = c4 * 4 + k;
            const bool nzx = (vp[k] != 0.0f);
            const bool nzA = nzx || (c == r);
            if (nzx) {
                unsigned p = atomicAdd(&rpos, 1u);
                unsigned idx = rbase + p;
                if (idx < NNZ_CAP) csr[idx] = (unsigned)c;
            }
            if (nzA) {
                unsigned p = atomicAdd(&colfill[c], 1u);
                unsigned idx = colptr[c] + p;
                if (idx < NNZ_CAP) csc[idx] = (unsigned)r;
                atomicAdd(&bins[batch[c]], dinv[c]);
            }
        }
    }
    __syncthreads();
    if (threadIdx.x < GG) s[(size_t)threadIdx.x * NN + r] = dinv[r] * bins[threadIdx.x];
}

// ---------------------------------------------------------------------------
// SpMM1:  M[r,:] = sum over nonzero columns c of row r of W1[c,:]
// One block per row, 1024 threads x float4 = 4096 cols.
// ---------------------------------------------------------------------------
__global__ __launch_bounds__(1024) void k_spmm1(const float* __restrict__ W1,
                                                const unsigned* __restrict__ rowptr,
                                                const unsigned* __restrict__ csr,
                                                float* __restrict__ M) {
    const int r = blockIdx.x;
    const int j = threadIdx.x;
    const unsigned beg = rowptr[r], end = rowptr[r + 1];
    float4 acc = make_float4(0.f, 0.f, 0.f, 0.f);
    for (unsigned e = beg; e < end; ++e) {
        const unsigned c = csr[e];
        float4 wv = reinterpret_cast<const float4*>(W1 + (size_t)c * HH)[j];
        acc.x += wv.x; acc.y += wv.y; acc.z += wv.z; acc.w += wv.w;
    }
    reinterpret_cast<float4*>(M + (size_t)r * HH)[j] = acc;
}

// ---------------------------------------------------------------------------
// Fused conv1 + pooled projection of h:
//   h[c,:] = relu(dinv[c] * sum_{rn in CSC(c)} dinv[rn]*M[rn,:] + b1)
//   t[g,:] += s[g,c] * h[c,:]        (h never materialized)
// Block = 64 rows x 1024-col chunk; 256 threads x float4.
// ---------------------------------------------------------------------------
#define R5 64
__global__ __launch_bounds__(256) void k_conv1_pool(const float* __restrict__ M,
                                                    const float* __restrict__ b1,
                                                    const float* __restrict__ dinv,
                                                    const float* __restrict__ s,
                                                    const unsigned* __restrict__ colptr,
                                                    const unsigned* __restrict__ csc,
                                                    float* __restrict__ t) {
    const int j = threadIdx.x;
    const int chunk = blockIdx.y * 1024;
    const int c0 = blockIdx.x * R5;
    float4 bv = reinterpret_cast<const float4*>(b1 + chunk)[j];
    float tacc[GG][4];
    #pragma unroll
    for (int g = 0; g < GG; ++g)
        #pragma unroll
        for (int k = 0; k < 4; ++k) tacc[g][k] = 0.0f;

    for (int cc = 0; cc < R5; ++cc) {
        const int c = c0 + cc;
        const unsigned beg = colptr[c], end = colptr[c + 1];
        const float dc = dinv[c];
        float4 acc = make_float4(0.f, 0.f, 0.f, 0.f);
        for (unsigned e = beg; e < end; ++e) {
            const unsigned rn = csc[e];
            const float coef = dinv[rn];
            float4 mv = reinterpret_cast<const float4*>(M + (size_t)rn * HH + chunk)[j];
            acc.x = fmaf(coef, mv.x, acc.x);
            acc.y = fmaf(coef, mv.y, acc.y);
            acc.z = fmaf(coef, mv.z, acc.z);
            acc.w = fmaf(coef, mv.w, acc.w);
        }
        const float hx = fmaxf(fmaf(dc, acc.x, bv.x), 0.0f);
        const float hy = fmaxf(fmaf(dc, acc.y, bv.y), 0.0f);
        const float hz = fmaxf(fmaf(dc, acc.z, bv.z), 0.0f);
        const float hw = fmaxf(fmaf(dc, acc.w, bv.w), 0.0f);
        #pragma unroll
        for (int g = 0; g < GG; ++g) {
            const float sv = s[(size_t)g * NN + c];
            tacc[g][0] = fmaf(sv, hx, tacc[g][0]);
            tacc[g][1] = fmaf(sv, hy, tacc[g][1]);
            tacc[g][2] = fmaf(sv, hz, tacc[g][2]);
            tacc[g][3] = fmaf(sv, hw, tacc[g][3]);
        }
    }
    #pragma unroll
    for (int g = 0; g < GG; ++g)
        #pragma unroll
        for (int k = 0; k < 4; ++k)
            atomicAdd(&t[g * HH + chunk + j * 4 + k], tacc[g][k]);
}

// out[g,n] = b2[n]  (then k_final atomically accumulates)
__global__ __launch_bounds__(256) void k_initout(const float* __restrict__ b2,
                                                 float* __restrict__ out) {
    const int i = blockIdx.x * 256 + threadIdx.x;
    if (i < GG * NN) out[i] = b2[i & (NN - 1)];
}

// ---------------------------------------------------------------------------
// Final: out[g, n] += sum_j (t[g,j]/cnt[g]) * W2[j, n]
// Grid (8 n-chunks of 1024) x (32 j-ranges of 128); 256 threads x float4.
// ---------------------------------------------------------------------------
__global__ __launch_bounds__(256) void k_final(const float* __restrict__ W2,
                                               const float* __restrict__ t,
                                               const unsigned* __restrict__ cnt,
                                               float* __restrict__ out) {
    __shared__ float tld[GG * 128];
    const int tj = threadIdx.x;
    const int j0 = blockIdx.y * 128;
    const int nbase = blockIdx.x * 1024;
    for (int i = threadIdx.x; i < GG * 128; i += 256) {
        const int g = i >> 7;
        const int jj = i & 127;
        unsigned c = cnt[g];
        if (c < 1u) c = 1u;
        tld[i] = t[(size_t)g * HH + j0 + jj] * (1.0f / (float)c);
    }
    __syncthreads();
    float4 acc[GG];
    #pragma unroll
    for (int g = 0; g < GG; ++g) acc[g] = make_float4(0.f, 0.f, 0.f, 0.f);
    for (int jj = 0; jj < 128; ++jj) {
        const int jv = j0 + jj;
        float4 w = reinterpret_cast<const float4*>(W2 + (size_t)jv * NN + nbase)[tj];
        #pragma unroll
        for (int g = 0; g < GG; ++g) {
            const float tv = tld[g * 128 + jj];
            acc[g].x = fmaf(tv, w.x, acc[g].x);
            acc[g].y = fmaf(tv, w.y, acc[g].y);
            acc[g].z = fmaf(tv, w.z, acc[g].z);
            acc[g].w = fmaf(tv, w.w, acc[g].w);
        }
    }
    #pragma unroll
    for (int g = 0; g < GG; ++g) {
        const size_t base = (size_t)g * NN + nbase + tj * 4;
        atomicAdd(&out[base + 0], acc[g].x);
        atomicAdd(&out[base + 1], acc[g].y);
        atomicAdd(&out[base + 2], acc[g].z);
        atomicAdd(&out[base + 3], acc[g].w);
    }
}

extern "C" void kernel_launch(void* const* d_in, const int* in_sizes, int n_in,
                              void* d_out, int out_size, void* d_ws, size_t ws_size,
                              hipStream_t stream) {
    const float* x  = (const float*)d_in[0];
    const float* W1 = (const float*)d_in[1];
    const float* b1 = (const float*)d_in[2];
    const float* W2 = (const float*)d_in[3];
    const float* b2 = (const float*)d_in[4];
    const int* batch = (const int*)d_in[5];
    float* out = (float*)d_out;

    char* ws = (char*)d_ws;
    size_t off = 0;
    auto alloc = [&](size_t bytes) -> char* {
        char* p = ws + off;
        off = (off + bytes + 255) & ~(size_t)255;
        return p;
    };
    float*    M       = (float*)   alloc((size_t)NN * HH * 4);
    char*     zbegin  = ws + off;
    float*    t       = (float*)   alloc((size_t)GG * HH * 4);
    float*    s       = (float*)   alloc((size_t)GG * NN * 4);
    float*    dinv    = (float*)   alloc((size_t)NN * 4);
    unsigned* colcnt  = (unsigned*)alloc((size_t)NN * 4);
    unsigned* rowcnt  = (unsigned*)alloc((size_t)NN * 4);
    unsigned* colptr  = (unsigned*)alloc((size_t)(NN + 1) * 4);
    unsigned* rowptr  = (unsigned*)alloc((size_t)(NN + 1) * 4);
    unsigned* colfill = (unsigned*)alloc((size_t)NN * 4);
    unsigned* cnt     = (unsigned*)alloc((size_t)GG * 4);
    char*     zend    = ws + off;
    unsigned* csr     = (unsigned*)alloc((size_t)NNZ_CAP * 4);
    unsigned* csc     = (unsigned*)alloc((size_t)NNZ_CAP * 4);
    (void)ws_size; (void)in_sizes; (void)n_in; (void)out_size;

    hipMemsetAsync(zbegin, 0, (size_t)(zend - zbegin), stream);

    k_count<<<NN, 256, 0, stream>>>(x, colcnt, rowcnt);
    k_scan<<<1, 1024, 0, stream>>>(rowcnt, colcnt, rowptr, colptr, dinv);
    k_batchcnt<<<NN / 256, 256, 0, stream>>>(batch, cnt);
    k_fill<<<NN, 256, 0, stream>>>(x, batch, dinv, rowptr, colptr, colfill, csr, csc, s);
    k_spmm1<<<NN, 1024, 0, stream>>>(W1, rowptr, csr, M);
    k_conv1_pool<<<dim3(NN / R5, HH / 1024), 256, 0, stream>>>(M, b1, dinv, s, colptr, csc, t);
    k_initout<<<(GG * NN) / 256, 256, 0, stream>>>(b2, out);
    k_final<<<dim3(NN / 1024, HH / 128), 256, 0, stream>>>(W2, t, cnt, out);
}

// Round 2
// 1419.727 us; speedup vs baseline: 1.1747x; 1.1747x over previous
//
#include <hip/hip_runtime.h>
#include <hip/hip_bf16.h>

#define NN 8192
#define HH 4096
#define GG 8
#define NNZ_CAP (1u << 20)

// ---------------------------------------------------------------------------
// bf16 helpers (packed 2x bf16 per u32; element 2q in low 16 bits)
// ---------------------------------------------------------------------------
__device__ inline unsigned bf16rne(float f) {
    unsigned u = __float_as_uint(f);
    unsigned r = 0x7fffu + ((u >> 16) & 1u);
    return (u + r) >> 16;
}
__device__ inline unsigned pack2(float lo, float hi) {
    return bf16rne(lo) | (bf16rne(hi) << 16);
}
__device__ inline void acc8(float* __restrict__ acc, uint4 v, float coef) {
    const unsigned* pu = reinterpret_cast<const unsigned*>(&v);
    #pragma unroll
    for (int q = 0; q < 4; ++q) {
        const unsigned u = pu[q];
        const float lo = __uint_as_float(u << 16);
        const float hi = __uint_as_float(u & 0xffff0000u);
        acc[2 * q]     = fmaf(coef, lo, acc[2 * q]);
        acc[2 * q + 1] = fmaf(coef, hi, acc[2 * q + 1]);
    }
}

// fp32 [elems] -> packed bf16; 8 elems per thread
__global__ __launch_bounds__(256) void k_cvt(const float* __restrict__ src,
                                             uint4* __restrict__ dst) {
    const size_t i = (size_t)blockIdx.x * 256 + threadIdx.x;
    const float4 a = reinterpret_cast<const float4*>(src)[2 * i];
    const float4 b = reinterpret_cast<const float4*>(src)[2 * i + 1];
    uint4 o;
    o.x = pack2(a.x, a.y);
    o.y = pack2(a.z, a.w);
    o.z = pack2(b.x, b.y);
    o.w = pack2(b.z, b.w);
    dst[i] = o;
}

// ---------------------------------------------------------------------------
// Pass 1: count nonzeros. rowcnt = nnz of x-pattern per row; colcnt = in-deg
// of A-pattern (x-pattern + forced diagonal) = GCN degree.
// ---------------------------------------------------------------------------
__global__ __launch_bounds__(256) void k_count(const float* __restrict__ x,
                                               unsigned* __restrict__ colcnt,
                                               unsigned* __restrict__ rowcnt) {
    const int r = blockIdx.x;
    const float4* xr = reinterpret_cast<const float4*>(x + (size_t)r * NN);
    __shared__ unsigned rc;
    if (threadIdx.x == 0) rc = 0u;
    __syncthreads();
    unsigned local = 0;
    #pragma unroll
    for (int i = 0; i < NN / (4 * 256); ++i) {
        const int c4 = i * 256 + threadIdx.x;
        float4 v = xr[c4];
        const float* vp = reinterpret_cast<const float*>(&v);
        #pragma unroll
        for (int k = 0; k < 4; ++k) {
            const int c = c4 * 4 + k;
            const bool nzx = (vp[k] != 0.0f);
            if (nzx) local++;
            if (nzx || (c == r)) atomicAdd(&colcnt[c], 1u);
        }
    }
    if (local) atomicAdd(&rc, local);
    __syncthreads();
    if (threadIdx.x == 0) rowcnt[r] = rc;
}

// ---------------------------------------------------------------------------
// Exclusive prefix sums + dinv = rsqrt(deg). Single block, 1024 threads.
// ---------------------------------------------------------------------------
__device__ void scan_one(const unsigned* __restrict__ cnt, unsigned* __restrict__ ptr,
                         unsigned* part) {
    const int t = threadIdx.x;
    unsigned v[8];
    unsigned sum = 0;
    #pragma unroll
    for (int k = 0; k < 8; ++k) { v[k] = cnt[t * 8 + k]; sum += v[k]; }
    part[t] = sum;
    __syncthreads();
    for (int off = 1; off < 1024; off <<= 1) {
        unsigned val = (t >= off) ? part[t - off] : 0u;
        __syncthreads();
        part[t] += val;
        __syncthreads();
    }
    unsigned base = (t == 0) ? 0u : part[t - 1];
    #pragma unroll
    for (int k = 0; k < 8; ++k) { ptr[t * 8 + k] = base; base += v[k]; }
    if (t == 1023) ptr[NN] = base;
    __syncthreads();
}

__global__ __launch_bounds__(1024) void k_scan(const unsigned* __restrict__ rowcnt,
                                               const unsigned* __restrict__ colcnt,
                                               unsigned* __restrict__ rowptr,
                                               unsigned* __restrict__ colptr,
                                               float* __restrict__ dinv) {
    __shared__ unsigned part[1024];
    scan_one(rowcnt, rowptr, part);
    __syncthreads();
    scan_one(colcnt, colptr, part);
    for (int i = threadIdx.x; i < NN; i += 1024)
        dinv[i] = rsqrtf((float)colcnt[i]);
}

__global__ __launch_bounds__(256) void k_batchcnt(const int* __restrict__ batch,
                                                  unsigned* __restrict__ cnt) {
    const int i = blockIdx.x * 256 + threadIdx.x;
    if (i < NN) atomicAdd(&cnt[batch[i]], 1u);
}

// ---------------------------------------------------------------------------
// Pass 2: fill CSR (x-pattern cols) and CSC (A-pattern rows); compute pooled
// adjacency s[g][r] = dinv[r] * sum_{c in row_A(r), batch[c]==g} dinv[c].
// ---------------------------------------------------------------------------
__global__ __launch_bounds__(256) void k_fill(const float* __restrict__ x,
                                              const int* __restrict__ batch,
                                              const float* __restrict__ dinv,
                                              const unsigned* __restrict__ rowptr,
                                              const unsigned* __restrict__ colptr,
                                              unsigned* __restrict__ colfill,
                                              unsigned* __restrict__ csr,
                                              unsigned* __restrict__ csc,
                                              float* __restrict__ s) {
    const int r = blockIdx.x;
    __shared__ unsigned rpos;
    __shared__ float bins[GG];
    if (threadIdx.x == 0) rpos = 0u;
    if (threadIdx.x < GG) bins[threadIdx.x] = 0.0f;
    __syncthreads();
    const unsigned rbase = rowptr[r];
    const float4* xr = reinterpret_cast<const float4*>(x + (size_t)r * NN);
    #pragma unroll
    for (int i = 0; i < NN / (4 * 256); ++i) {
        const int c4 = i * 256 + threadIdx.x;
        float4 v = xr[c4];
        const float* vp = reinterpret_cast<const float*>(&v);
        #pragma unroll
        for (int k = 0; k < 4; ++k) {
            const int c = c4 * 4 + k;
            const bool nzx = (vp[k] != 0.0f);
            const bool nzA = nzx || (c == r);
            if (nzx) {
                unsigned p = atomicAdd(&rpos, 1u);
                unsigned idx = rbase + p;
                if (idx < NNZ_CAP) csr[idx] = (unsigned)c;
            }
            if (nzA) {
                unsigned p = atomicAdd(&colfill[c], 1u);
                unsigned idx = colptr[c] + p;
                if (idx < NNZ_CAP) csc[idx] = (unsigned)r;
                atomicAdd(&bins[batch[c]], dinv[c]);
            }
        }
    }
    __syncthreads();
    if (threadIdx.x < GG) s[(size_t)threadIdx.x * NN + r] = dinv[r] * bins[threadIdx.x];
}

// ---------------------------------------------------------------------------
// SpMM1: Mh[r,:] = bf16( sum_{c in CSR(r)} W1h[c,:] ).  512 thr x 8 bf16.
// ---------------------------------------------------------------------------
__global__ __launch_bounds__(512) void k_spmm1(const uint4* __restrict__ W1h,
                                               const unsigned* __restrict__ rowptr,
                                               const unsigned* __restrict__ csr,
                                               uint4* __restrict__ Mh) {
    const int r = blockIdx.x;
    const int j = threadIdx.x;
    const unsigned beg = rowptr[r], end = rowptr[r + 1];
    float acc[8];
    #pragma unroll
    for (int q = 0; q < 8; ++q) acc[q] = 0.0f;
    for (unsigned e = beg; e < end; ++e) {
        const unsigned c = csr[e];
        uint4 v = W1h[(size_t)c * (HH / 8) + j];
        acc8(acc, v, 1.0f);
    }
    uint4 o;
    o.x = pack2(acc[0], acc[1]);
    o.y = pack2(acc[2], acc[3]);
    o.z = pack2(acc[4], acc[5]);
    o.w = pack2(acc[6], acc[7]);
    Mh[(size_t)r * (HH / 8) + j] = o;
}

// ---------------------------------------------------------------------------
// Fused conv1 + pooled projection:
//   h[c,:] = relu(dinv[c] * sum_{rn in CSC(c)} dinv[rn]*Mh[rn,:] + b1)
//   t[g,:] += s[g,c] * h[c,:]
// 512 threads cover the full H row (8 bf16 each); R5=16 cols/block.
// ---------------------------------------------------------------------------
#define R5 16
__global__ __launch_bounds__(512) void k_conv1_pool(const uint4* __restrict__ Mh,
                                                    const float* __restrict__ b1,
                                                    const float* __restrict__ dinv,
                                                    const float* __restrict__ s,
                                                    const unsigned* __restrict__ colptr,
                                                    const unsigned* __restrict__ csc,
                                                    float* __restrict__ t) {
    const int j = threadIdx.x;
    const int c0 = blockIdx.x * R5;
    __shared__ float s_tile[GG * R5];
    __shared__ float dinv_tile[R5];
    if (threadIdx.x < GG * R5) {
        const int g = threadIdx.x / R5;
        const int cc = threadIdx.x % R5;
        s_tile[threadIdx.x] = s[(size_t)g * NN + c0 + cc];
    }
    if (threadIdx.x < R5) dinv_tile[threadIdx.x] = dinv[c0 + threadIdx.x];
    __syncthreads();

    float bv[8];
    {
        const float4 a = reinterpret_cast<const float4*>(b1)[2 * j];
        const float4 b = reinterpret_cast<const float4*>(b1)[2 * j + 1];
        bv[0] = a.x; bv[1] = a.y; bv[2] = a.z; bv[3] = a.w;
        bv[4] = b.x; bv[5] = b.y; bv[6] = b.z; bv[7] = b.w;
    }
    float tacc[GG][8];
    #pragma unroll
    for (int g = 0; g < GG; ++g)
        #pragma unroll
        for (int q = 0; q < 8; ++q) tacc[g][q] = 0.0f;

    for (int cc = 0; cc < R5; ++cc) {
        const int c = c0 + cc;
        const unsigned beg = colptr[c], end = colptr[c + 1];
        float acc[8];
        #pragma unroll
        for (int q = 0; q < 8; ++q) acc[q] = 0.0f;
        for (unsigned e = beg; e < end; ++e) {
            const unsigned rn = csc[e];
            const float coef = dinv[rn];
            uint4 v = Mh[(size_t)rn * (HH / 8) + j];
            acc8(acc, v, coef);
        }
        const float dc = dinv_tile[cc];
        float h[8];
        #pragma unroll
        for (int q = 0; q < 8; ++q) h[q] = fmaxf(fmaf(dc, acc[q], bv[q]), 0.0f);
        #pragma unroll
        for (int g = 0; g < GG; ++g) {
            const float sv = s_tile[g * R5 + cc];
            #pragma unroll
            for (int q = 0; q < 8; ++q) tacc[g][q] = fmaf(sv, h[q], tacc[g][q]);
        }
    }
    #pragma unroll
    for (int g = 0; g < GG; ++g)
        #pragma unroll
        for (int q = 0; q < 8; ++q)
            atomicAdd(&t[g * HH + j * 8 + q], tacc[g][q]);
}

// out[g,n] = b2[n]
__global__ __launch_bounds__(256) void k_initout(const float* __restrict__ b2,
                                                 float* __restrict__ out) {
    const int i = blockIdx.x * 256 + threadIdx.x;
    if (i < GG * NN) out[i] = b2[i & (NN - 1)];
}

// ---------------------------------------------------------------------------
// Final: out[g, n] += sum_j (t[g,j]/cnt[g]) * W2[j, n]
// ---------------------------------------------------------------------------
__global__ __launch_bounds__(256) void k_final(const float* __restrict__ W2,
                                               const float* __restrict__ t,
                                               const unsigned* __restrict__ cnt,
                                               float* __restrict__ out) {
    __shared__ float tld[GG * 128];
    const int tj = threadIdx.x;
    const int j0 = blockIdx.y * 128;
    const int nbase = blockIdx.x * 1024;
    for (int i = threadIdx.x; i < GG * 128; i += 256) {
        const int g = i >> 7;
        const int jj = i & 127;
        unsigned c = cnt[g];
        if (c < 1u) c = 1u;
        tld[i] = t[(size_t)g * HH + j0 + jj] * (1.0f / (float)c);
    }
    __syncthreads();
    float4 acc[GG];
    #pragma unroll
    for (int g = 0; g < GG; ++g) acc[g] = make_float4(0.f, 0.f, 0.f, 0.f);
    for (int jj = 0; jj < 128; ++jj) {
        const int jv = j0 + jj;
        float4 w = reinterpret_cast<const float4*>(W2 + (size_t)jv * NN + nbase)[tj];
        #pragma unroll
        for (int g = 0; g < GG; ++g) {
            const float tv = tld[g * 128 + jj];
            acc[g].x = fmaf(tv, w.x, acc[g].x);
            acc[g].y = fmaf(tv, w.y, acc[g].y);
            acc[g].z = fmaf(tv, w.z, acc[g].z);
            acc[g].w = fmaf(tv, w.w, acc[g].w);
        }
    }
    #pragma unroll
    for (int g = 0; g < GG; ++g) {
        const size_t base = (size_t)g * NN + nbase + tj * 4;
        atomicAdd(&out[base + 0], acc[g].x);
        atomicAdd(&out[base + 1], acc[g].y);
        atomicAdd(&out[base + 2], acc[g].z);
        atomicAdd(&out[base + 3], acc[g].w);
    }
}

extern "C" void kernel_launch(void* const* d_in, const int* in_sizes, int n_in,
                              void* d_out, int out_size, void* d_ws, size_t ws_size,
                              hipStream_t stream) {
    const float* x  = (const float*)d_in[0];
    const float* W1 = (const float*)d_in[1];
    const float* b1 = (const float*)d_in[2];
    const float* W2 = (const float*)d_in[3];
    const float* b2 = (const float*)d_in[4];
    const int* batch = (const int*)d_in[5];
    float* out = (float*)d_out;

    char* ws = (char*)d_ws;
    size_t off = 0;
    auto alloc = [&](size_t bytes) -> char* {
        char* p = ws + off;
        off = (off + bytes + 255) & ~(size_t)255;
        return p;
    };
    uint4*    Mh      = (uint4*)   alloc((size_t)NN * HH * 2);   // bf16 M
    uint4*    W1h     = (uint4*)   alloc((size_t)NN * HH * 2);   // bf16 W1
    char*     zbegin  = ws + off;
    float*    t       = (float*)   alloc((size_t)GG * HH * 4);
    float*    s       = (float*)   alloc((size_t)GG * NN * 4);
    float*    dinv    = (float*)   alloc((size_t)NN * 4);
    unsigned* colcnt  = (unsigned*)alloc((size_t)NN * 4);
    unsigned* rowcnt  = (unsigned*)alloc((size_t)NN * 4);
    unsigned* colptr  = (unsigned*)alloc((size_t)(NN + 1) * 4);
    unsigned* rowptr  = (unsigned*)alloc((size_t)(NN + 1) * 4);
    unsigned* colfill = (unsigned*)alloc((size_t)NN * 4);
    unsigned* cnt     = (unsigned*)alloc((size_t)GG * 4);
    char*     zend    = ws + off;
    unsigned* csr     = (unsigned*)alloc((size_t)NNZ_CAP * 4);
    unsigned* csc     = (unsigned*)alloc((size_t)NNZ_CAP * 4);
    (void)ws_size; (void)in_sizes; (void)n_in; (void)out_size;

    hipMemsetAsync(zbegin, 0, (size_t)(zend - zbegin), stream);

    k_cvt<<<(NN * HH / 8) / 256, 256, 0, stream>>>(W1, (uint4*)W1h);
    k_count<<<NN, 256, 0, stream>>>(x, colcnt, rowcnt);
    k_scan<<<1, 1024, 0, stream>>>(rowcnt, colcnt, rowptr, colptr, dinv);
    k_batchcnt<<<NN / 256, 256, 0, stream>>>(batch, cnt);
    k_fill<<<NN, 256, 0, stream>>>(x, batch, dinv, rowptr, colptr, colfill, csr, csc, s);
    k_spmm1<<<NN, 512, 0, stream>>>(W1h, rowptr, csr, Mh);
    k_conv1_pool<<<NN / R5, 512, 0, stream>>>(Mh, b1, dinv, s, colptr, csc, t);
    k_initout<<<(GG * NN) / 256, 256, 0, stream>>>(b2, out);
    k_final<<<dim3(NN / 1024, HH / 128), 256, 0, stream>>>(W2, t, cnt, out);
}

// Round 3
// 1150.476 us; speedup vs baseline: 1.4496x; 1.2340x over previous
//
#include <hip/hip_runtime.h>
#include <hip/hip_bf16.h>

#define NN 8192
#define HH 4096
#define GG 8
#define NNZ_CAP (1u << 20)
#define MAXDEG 512

// ---------------------------------------------------------------------------
// bf16 helpers (packed 2x bf16 per u32; element 2q in low 16 bits)
// ---------------------------------------------------------------------------
__device__ inline unsigned bf16rne(float f) {
    unsigned u = __float_as_uint(f);
    unsigned r = 0x7fffu + ((u >> 16) & 1u);
    return (u + r) >> 16;
}
__device__ inline unsigned pack2(float lo, float hi) {
    return bf16rne(lo) | (bf16rne(hi) << 16);
}
__device__ inline void acc8(float* __restrict__ acc, uint4 v) {
    const unsigned* pu = reinterpret_cast<const unsigned*>(&v);
    #pragma unroll
    for (int q = 0; q < 4; ++q) {
        const unsigned u = pu[q];
        acc[2 * q]     += __uint_as_float(u << 16);
        acc[2 * q + 1] += __uint_as_float(u & 0xffff0000u);
    }
}
__device__ inline void unpack8(uint4 v, float* __restrict__ h) {
    const unsigned* pu = reinterpret_cast<const unsigned*>(&v);
    #pragma unroll
    for (int q = 0; q < 4; ++q) {
        const unsigned u = pu[q];
        h[2 * q]     = __uint_as_float(u << 16);
        h[2 * q + 1] = __uint_as_float(u & 0xffff0000u);
    }
}

// fp32 -> packed bf16; 8 elems per thread
__global__ __launch_bounds__(256) void k_cvt(const float* __restrict__ src,
                                             uint4* __restrict__ dst) {
    const size_t i = (size_t)blockIdx.x * 256 + threadIdx.x;
    const float4 a = reinterpret_cast<const float4*>(src)[2 * i];
    const float4 b = reinterpret_cast<const float4*>(src)[2 * i + 1];
    uint4 o;
    o.x = pack2(a.x, a.y);
    o.y = pack2(a.z, a.w);
    o.z = pack2(b.x, b.y);
    o.w = pack2(b.z, b.w);
    dst[i] = o;
}

// ---------------------------------------------------------------------------
// Pass 1: rowcnt = nnz of x-pattern per row; colcnt = in-degree of A-pattern
// (x-pattern + forced diagonal) = GCN degree.
// ---------------------------------------------------------------------------
__global__ __launch_bounds__(256) void k_count(const float* __restrict__ x,
                                               unsigned* __restrict__ colcnt,
                                               unsigned* __restrict__ rowcnt) {
    const int r = blockIdx.x;
    const float4* xr = reinterpret_cast<const float4*>(x + (size_t)r * NN);
    __shared__ unsigned rc;
    if (threadIdx.x == 0) rc = 0u;
    __syncthreads();
    unsigned local = 0;
    #pragma unroll
    for (int i = 0; i < NN / (4 * 256); ++i) {
        const int c4 = i * 256 + threadIdx.x;
        float4 v = xr[c4];
        const float* vp = reinterpret_cast<const float*>(&v);
        #pragma unroll
        for (int k = 0; k < 4; ++k) {
            const int c = c4 * 4 + k;
            const bool nzx = (vp[k] != 0.0f);
            if (nzx) local++;
            if (nzx || (c == r)) atomicAdd(&colcnt[c], 1u);
        }
    }
    if (local) atomicAdd(&rc, local);
    __syncthreads();
    if (threadIdx.x == 0) rowcnt[r] = rc;
}

// ---------------------------------------------------------------------------
// Exclusive prefix sums + dinv = rsqrt(deg). Single block, 1024 threads.
// ---------------------------------------------------------------------------
__device__ void scan_one(const unsigned* __restrict__ cnt, unsigned* __restrict__ ptr,
                         unsigned* part) {
    const int t = threadIdx.x;
    unsigned v[8];
    unsigned sum = 0;
    #pragma unroll
    for (int k = 0; k < 8; ++k) { v[k] = cnt[t * 8 + k]; sum += v[k]; }
    part[t] = sum;
    __syncthreads();
    for (int off = 1; off < 1024; off <<= 1) {
        unsigned val = (t >= off) ? part[t - off] : 0u;
        __syncthreads();
        part[t] += val;
        __syncthreads();
    }
    unsigned base = (t == 0) ? 0u : part[t - 1];
    #pragma unroll
    for (int k = 0; k < 8; ++k) { ptr[t * 8 + k] = base; base += v[k]; }
    if (t == 1023) ptr[NN] = base;
    __syncthreads();
}

__global__ __launch_bounds__(1024) void k_scan(const unsigned* __restrict__ rowcnt,
                                               const unsigned* __restrict__ colcnt,
                                               unsigned* __restrict__ rowptr,
                                               unsigned* __restrict__ colptr,
                                               float* __restrict__ dinv) {
    __shared__ unsigned part[1024];
    scan_one(rowcnt, rowptr, part);
    __syncthreads();
    scan_one(colcnt, colptr, part);
    for (int i = threadIdx.x; i < NN; i += 1024)
        dinv[i] = rsqrtf((float)colcnt[i]);
}

__global__ __launch_bounds__(256) void k_batchcnt(const int* __restrict__ batch,
                                                  unsigned* __restrict__ cnt) {
    const int i = blockIdx.x * 256 + threadIdx.x;
    if (i < NN) atomicAdd(&cnt[batch[i]], 1u);
}

// ---------------------------------------------------------------------------
// Pass 2: fill CSR (x-pattern cols) and CSC (A-pattern rows); pooled adjacency
// s[g][r] = dinv[r] * sum_{c in row_A(r), batch[c]==g} dinv[c].
// ---------------------------------------------------------------------------
__global__ __launch_bounds__(256) void k_fill(const float* __restrict__ x,
                                              const int* __restrict__ batch,
                                              const float* __restrict__ dinv,
                                              const unsigned* __restrict__ rowptr,
                                              const unsigned* __restrict__ colptr,
                                              unsigned* __restrict__ colfill,
                                              unsigned* __restrict__ csr,
                                              unsigned* __restrict__ csc,
                                              float* __restrict__ s) {
    const int r = blockIdx.x;
    __shared__ unsigned rpos;
    __shared__ float bins[GG];
    if (threadIdx.x == 0) rpos = 0u;
    if (threadIdx.x < GG) bins[threadIdx.x] = 0.0f;
    __syncthreads();
    const unsigned rbase = rowptr[r];
    const float4* xr = reinterpret_cast<const float4*>(x + (size_t)r * NN);
    #pragma unroll
    for (int i = 0; i < NN / (4 * 256); ++i) {
        const int c4 = i * 256 + threadIdx.x;
        float4 v = xr[c4];
        const float* vp = reinterpret_cast<const float*>(&v);
        #pragma unroll
        for (int k = 0; k < 4; ++k) {
            const int c = c4 * 4 + k;
            const bool nzx = (vp[k] != 0.0f);
            const bool nzA = nzx || (c == r);
            if (nzx) {
                unsigned p = atomicAdd(&rpos, 1u);
                unsigned idx = rbase + p;
                if (idx < NNZ_CAP) csr[idx] = (unsigned)c;
            }
            if (nzA) {
                unsigned p = atomicAdd(&colfill[c], 1u);
                unsigned idx = colptr[c] + p;
                if (idx < NNZ_CAP) csc[idx] = (unsigned)r;
                atomicAdd(&bins[batch[c]], dinv[c]);
            }
        }
    }
    __syncthreads();
    if (threadIdx.x < GG) s[(size_t)threadIdx.x * NN + r] = dinv[r] * bins[threadIdx.x];
}

// ---------------------------------------------------------------------------
// SpMM1: Mh[r,:] = bf16( dinv[r] * sum_{c in CSR(r)} W1h[c,:] ).
// One row per block.x, H split in 2 chunks (blockIdx.y); 256 thr x 8 bf16.
// Edge list staged in LDS; gather loop unrolled x4 for MLP.
// ---------------------------------------------------------------------------
__global__ __launch_bounds__(256) void k_spmm1(const uint4* __restrict__ W1h,
                                               const unsigned* __restrict__ rowptr,
                                               const unsigned* __restrict__ csr,
                                               const float* __restrict__ dinv,
                                               uint4* __restrict__ Mh) {
    const int r = blockIdx.x;
    const int j = blockIdx.y * 256 + threadIdx.x;   // uint4 column index
    const unsigned beg = rowptr[r];
    const unsigned deg = rowptr[r + 1] - beg;
    __shared__ unsigned eidx[MAXDEG];
    const unsigned degc = deg < MAXDEG ? deg : MAXDEG;
    for (unsigned i = threadIdx.x; i < degc; i += 256) eidx[i] = csr[beg + i];
    __syncthreads();

    float acc[8];
    #pragma unroll
    for (int q = 0; q < 8; ++q) acc[q] = 0.0f;
    unsigned e = 0;
    for (; e + 4 <= degc; e += 4) {
        const uint4 v0 = W1h[(size_t)eidx[e + 0] * (HH / 8) + j];
        const uint4 v1 = W1h[(size_t)eidx[e + 1] * (HH / 8) + j];
        const uint4 v2 = W1h[(size_t)eidx[e + 2] * (HH / 8) + j];
        const uint4 v3 = W1h[(size_t)eidx[e + 3] * (HH / 8) + j];
        acc8(acc, v0); acc8(acc, v1); acc8(acc, v2); acc8(acc, v3);
    }
    for (; e < degc; ++e) acc8(acc, W1h[(size_t)eidx[e] * (HH / 8) + j]);
    for (unsigned ee = MAXDEG; ee < deg; ++ee)      // never in practice
        acc8(acc, W1h[(size_t)csr[beg + ee] * (HH / 8) + j]);

    const float dr = dinv[r];
    uint4 o;
    o.x = pack2(dr * acc[0], dr * acc[1]);
    o.y = pack2(dr * acc[2], dr * acc[3]);
    o.z = pack2(dr * acc[4], dr * acc[5]);
    o.w = pack2(dr * acc[6], dr * acc[7]);
    Mh[(size_t)r * (HH / 8) + j] = o;
}

// ---------------------------------------------------------------------------
// conv1: hB[c,:] = bf16( relu(dinv[c] * sum_{rn in CSC(c)} Mh[rn,:] + b1) )
// (Mh is pre-scaled by dinv[rn].)  One column per block.x, 2 H-chunks.
// ---------------------------------------------------------------------------
__global__ __launch_bounds__(256) void k_conv1(const uint4* __restrict__ Mh,
                                               const float* __restrict__ b1,
                                               const float* __restrict__ dinv,
                                               const unsigned* __restrict__ colptr,
                                               const unsigned* __restrict__ csc,
                                               uint4* __restrict__ hB) {
    const int c = blockIdx.x;
    const int j = blockIdx.y * 256 + threadIdx.x;
    const unsigned beg = colptr[c];
    const unsigned deg = colptr[c + 1] - beg;
    __shared__ unsigned eidx[MAXDEG];
    const unsigned degc = deg < MAXDEG ? deg : MAXDEG;
    for (unsigned i = threadIdx.x; i < degc; i += 256) eidx[i] = csc[beg + i];
    __syncthreads();

    float acc[8];
    #pragma unroll
    for (int q = 0; q < 8; ++q) acc[q] = 0.0f;
    unsigned e = 0;
    for (; e + 4 <= degc; e += 4) {
        const uint4 v0 = Mh[(size_t)eidx[e + 0] * (HH / 8) + j];
        const uint4 v1 = Mh[(size_t)eidx[e + 1] * (HH / 8) + j];
        const uint4 v2 = Mh[(size_t)eidx[e + 2] * (HH / 8) + j];
        const uint4 v3 = Mh[(size_t)eidx[e + 3] * (HH / 8) + j];
        acc8(acc, v0); acc8(acc, v1); acc8(acc, v2); acc8(acc, v3);
    }
    for (; e < degc; ++e) acc8(acc, Mh[(size_t)eidx[e] * (HH / 8) + j]);
    for (unsigned ee = MAXDEG; ee < deg; ++ee)      // never in practice
        acc8(acc, Mh[(size_t)csc[beg + ee] * (HH / 8) + j]);

    const float dc = dinv[c];
    float bv[8];
    {
        const float4 a = reinterpret_cast<const float4*>(b1)[2 * j];
        const float4 b = reinterpret_cast<const float4*>(b1)[2 * j + 1];
        bv[0] = a.x; bv[1] = a.y; bv[2] = a.z; bv[3] = a.w;
        bv[4] = b.x; bv[5] = b.y; bv[6] = b.z; bv[7] = b.w;
    }
    float h[8];
    #pragma unroll
    for (int q = 0; q < 8; ++q) h[q] = fmaxf(fmaf(dc, acc[q], bv[q]), 0.0f);
    uint4 o;
    o.x = pack2(h[0], h[1]);
    o.y = pack2(h[2], h[3]);
    o.z = pack2(h[4], h[5]);
    o.w = pack2(h[6], h[7]);
    hB[(size_t)c * (HH / 8) + j] = o;
}

// ---------------------------------------------------------------------------
// Pool: t[g,:] += sum_c s[g,c] * h[c,:].  Streaming read of hB (L3-resident).
// grid = (HH/2048) x (NN/PC); 256 thr x 8 elems.
// ---------------------------------------------------------------------------
#define PC 32
__global__ __launch_bounds__(256) void k_pool(const uint4* __restrict__ hB,
                                              const float* __restrict__ s,
                                              float* __restrict__ t) {
    const int j = blockIdx.x * 256 + threadIdx.x;
    const int c0 = blockIdx.y * PC;
    __shared__ float s_t[GG * PC];
    if (threadIdx.x < GG * PC) {
        const int g = threadIdx.x / PC;
        const int cc = threadIdx.x % PC;
        s_t[threadIdx.x] = s[(size_t)g * NN + c0 + cc];
    }
    __syncthreads();
    float tacc[GG][8];
    #pragma unroll
    for (int g = 0; g < GG; ++g)
        #pragma unroll
        for (int q = 0; q < 8; ++q) tacc[g][q] = 0.0f;
    for (int cc = 0; cc < PC; ++cc) {
        const uint4 v = hB[(size_t)(c0 + cc) * (HH / 8) + j];
        float hv[8];
        unpack8(v, hv);
        #pragma unroll
        for (int g = 0; g < GG; ++g) {
            const float sv = s_t[g * PC + cc];
            #pragma unroll
            for (int q = 0; q < 8; ++q) tacc[g][q] = fmaf(sv, hv[q], tacc[g][q]);
        }
    }
    #pragma unroll
    for (int g = 0; g < GG; ++g)
        #pragma unroll
        for (int q = 0; q < 8; ++q)
            atomicAdd(&t[g * HH + j * 8 + q], tacc[g][q]);
}

// out[g,n] = b2[n]
__global__ __launch_bounds__(256) void k_initout(const float* __restrict__ b2,
                                                 float* __restrict__ out) {
    const int i = blockIdx.x * 256 + threadIdx.x;
    if (i < GG * NN) out[i] = b2[i & (NN - 1)];
}

// ---------------------------------------------------------------------------
// Final: out[g, n] += sum_j (t[g,j]/cnt[g]) * W2[j, n]
// ---------------------------------------------------------------------------
__global__ __launch_bounds__(256) void k_final(const float* __restrict__ W2,
                                               const float* __restrict__ t,
                                               const unsigned* __restrict__ cnt,
                                               float* __restrict__ out) {
    __shared__ float tld[GG * 128];
    const int tj = threadIdx.x;
    const int j0 = blockIdx.y * 128;
    const int nbase = blockIdx.x * 1024;
    for (int i = threadIdx.x; i < GG * 128; i += 256) {
        const int g = i >> 7;
        const int jj = i & 127;
        unsigned c = cnt[g];
        if (c < 1u) c = 1u;
        tld[i] = t[(size_t)g * HH + j0 + jj] * (1.0f / (float)c);
    }
    __syncthreads();
    float4 acc[GG];
    #pragma unroll
    for (int g = 0; g < GG; ++g) acc[g] = make_float4(0.f, 0.f, 0.f, 0.f);
    for (int jj = 0; jj < 128; ++jj) {
        const int jv = j0 + jj;
        float4 w = reinterpret_cast<const float4*>(W2 + (size_t)jv * NN + nbase)[tj];
        #pragma unroll
        for (int g = 0; g < GG; ++g) {
            const float tv = tld[g * 128 + jj];
            acc[g].x = fmaf(tv, w.x, acc[g].x);
            acc[g].y = fmaf(tv, w.y, acc[g].y);
            acc[g].z = fmaf(tv, w.z, acc[g].z);
            acc[g].w = fmaf(tv, w.w, acc[g].w);
        }
    }
    #pragma unroll
    for (int g = 0; g < GG; ++g) {
        const size_t base = (size_t)g * NN + nbase + tj * 4;
        atomicAdd(&out[base + 0], acc[g].x);
        atomicAdd(&out[base + 1], acc[g].y);
        atomicAdd(&out[base + 2], acc[g].z);
        atomicAdd(&out[base + 3], acc[g].w);
    }
}

extern "C" void kernel_launch(void* const* d_in, const int* in_sizes, int n_in,
                              void* d_out, int out_size, void* d_ws, size_t ws_size,
                              hipStream_t stream) {
    const float* x  = (const float*)d_in[0];
    const float* W1 = (const float*)d_in[1];
    const float* b1 = (const float*)d_in[2];
    const float* W2 = (const float*)d_in[3];
    const float* b2 = (const float*)d_in[4];
    const int* batch = (const int*)d_in[5];
    float* out = (float*)d_out;

    char* ws = (char*)d_ws;
    size_t off = 0;
    auto alloc = [&](size_t bytes) -> char* {
        char* p = ws + off;
        off = (off + bytes + 255) & ~(size_t)255;
        return p;
    };
    uint4*    Mh      = (uint4*)   alloc((size_t)NN * HH * 2);   // bf16 M (dinv-scaled)
    uint4*    W1h     = (uint4*)   alloc((size_t)NN * HH * 2);   // bf16 W1; REUSED as hB
    uint4*    hB      = W1h;   // h overlays W1h (W1h dead after k_spmm1; stream-serial)
    char*     zbegin  = ws + off;
    float*    t       = (float*)   alloc((size_t)GG * HH * 4);
    float*    s       = (float*)   alloc((size_t)GG * NN * 4);
    float*    dinv    = (float*)   alloc((size_t)NN * 4);
    unsigned* colcnt  = (unsigned*)alloc((size_t)NN * 4);
    unsigned* rowcnt  = (unsigned*)alloc((size_t)NN * 4);
    unsigned* colptr  = (unsigned*)alloc((size_t)(NN + 1) * 4);
    unsigned* rowptr  = (unsigned*)alloc((size_t)(NN + 1) * 4);
    unsigned* colfill = (unsigned*)alloc((size_t)NN * 4);
    unsigned* cnt     = (unsigned*)alloc((size_t)GG * 4);
    char*     zend    = ws + off;
    unsigned* csr     = (unsigned*)alloc((size_t)NNZ_CAP * 4);
    unsigned* csc     = (unsigned*)alloc((size_t)NNZ_CAP * 4);
    (void)ws_size; (void)in_sizes; (void)n_in; (void)out_size;

    hipMemsetAsync(zbegin, 0, (size_t)(zend - zbegin), stream);

    k_cvt<<<(NN * HH / 8) / 256, 256, 0, stream>>>(W1, (uint4*)W1h);
    k_count<<<NN, 256, 0, stream>>>(x, colcnt, rowcnt);
    k_scan<<<1, 1024, 0, stream>>>(rowcnt, colcnt, rowptr, colptr, dinv);
    k_batchcnt<<<NN / 256, 256, 0, stream>>>(batch, cnt);
    k_fill<<<NN, 256, 0, stream>>>(x, batch, dinv, rowptr, colptr, colfill, csr, csc, s);
    k_spmm1<<<dim3(NN, 2), 256, 0, stream>>>(W1h, rowptr, csr, dinv, Mh);
    k_conv1<<<dim3(NN, 2), 256, 0, stream>>>(Mh, b1, dinv, colptr, csc, hB);
    k_pool<<<dim3(HH / 2048, NN / PC), 256, 0, stream>>>(hB, s, t);
    k_initout<<<(GG * NN) / 256, 256, 0, stream>>>(b2, out);
    k_final<<<dim3(NN / 1024, HH / 128), 256, 0, stream>>>(W2, t, cnt, out);
}